// Round 5
// baseline (80.516 us; speedup 1.0000x reference)
//
#include <hip/hip_runtime.h>
#include <math.h>

#define NUM_GRAPHS 512
#define D 128
#define DOTS_GRID (2 * NUM_GRAPHS)

__device__ inline int lower_bound_i(const int* __restrict__ b, int n, int v) {
    int lo = 0, hi = n;
    while (lo < hi) {
        int mid = (lo + hi) >> 1;
        if (b[mid] < v) lo = mid + 1; else hi = mid;
    }
    return lo;
}

__device__ inline void add4(float4& a, const float4 v) {
    a.x += v.x; a.y += v.y; a.z += v.z; a.w += v.w;
}

// K0: one binary search per (segment, modality) + zero the accumulators/ticket
// (replaces the 38 µs fillBuffer dispatch seen in R3's profile).
__global__ void bounds_kernel(const int* __restrict__ b1,
                              const int* __restrict__ b2,
                              int* __restrict__ off,
                              float* __restrict__ sums,
                              int* __restrict__ ticket, int N) {
    const int t = blockIdx.x * blockDim.x + threadIdx.x;
    if (t < NUM_GRAPHS)            off[t] = lower_bound_i(b1, N, t);
    else if (t < 2 * NUM_GRAPHS)   off[t] = lower_bound_i(b2, N, t - NUM_GRAPHS);
    if (t == 0) { sums[0] = 0.f; sums[1] = 0.f; *ticket = 0; }
}

// K1: segment sum + L2-normalize, store normalized g. grid (512,2), block 256.
// Thread t: row-group r=t>>5 (8 rows/group), float4 col c=t&31.
// 4 independent accumulators -> 4 loads in flight per lane.
__global__ __launch_bounds__(256) void seg_norm_kernel(const float* __restrict__ z1,
                                                       const float* __restrict__ z2,
                                                       const int* __restrict__ off,
                                                       float* __restrict__ g1n,
                                                       float* __restrict__ g2n,
                                                       int N) {
    const int s = blockIdx.x;
    const int w = blockIdx.y;
    const float* z = w ? z2 : z1;
    float*       g = w ? g2n : g1n;
    const int*   o = off + w * NUM_GRAPHS;
    const int start = o[s];
    const int end   = (s == NUM_GRAPHS - 1) ? N : o[s + 1];

    const int t = threadIdx.x;
    const int r = t >> 5;   // 0..7
    const int c = t & 31;   // float4 col
    const float4* Z = reinterpret_cast<const float4*>(z);

    float4 a0 = make_float4(0.f, 0.f, 0.f, 0.f), a1 = a0, a2 = a0, a3 = a0;
    int row = start + r;
    for (; row + 24 < end; row += 32) {
        float4 v0 = Z[(size_t)row * 32 + c];
        float4 v1 = Z[(size_t)(row + 8)  * 32 + c];
        float4 v2 = Z[(size_t)(row + 16) * 32 + c];
        float4 v3 = Z[(size_t)(row + 24) * 32 + c];
        add4(a0, v0); add4(a1, v1); add4(a2, v2); add4(a3, v3);
    }
    for (; row < end; row += 8) add4(a0, Z[(size_t)row * 32 + c]);
    add4(a0, a1); add4(a2, a3); add4(a0, a2);

    __shared__ float4 part[8][32];
    part[r][c] = a0;
    __syncthreads();
    if (t < 32) {
        float4 sum = part[0][t];
#pragma unroll
        for (int gg = 1; gg < 8; ++gg) add4(sum, part[gg][t]);
        float ss = sum.x * sum.x + sum.y * sum.y + sum.z * sum.z + sum.w * sum.w;
#pragma unroll
        for (int m = 1; m <= 16; m <<= 1) ss += __shfl_xor(ss, m, 64);
        const float inv = 1.0f / fmaxf(sqrtf(ss), 1e-12f);
        sum.x *= inv; sum.y *= inv; sum.z *= inv; sum.w *= inv;
        reinterpret_cast<float4*>(g)[(size_t)s * 32 + t] = sum;
    }
}

// K2: per-row dots + JSD. grid (512,2) flattened to 1024 blocks, block 256.
// Quad-per-row: q=t&3 owns 32 floats (8 float4). g vectors in registers.
// Last block (ticket) writes the final scalar -> no separate finalize dispatch.
__global__ __launch_bounds__(256) void dots_kernel(const float* __restrict__ z1,
                                                   const float* __restrict__ z2,
                                                   const int* __restrict__ off,
                                                   const float* __restrict__ g1n,
                                                   const float* __restrict__ g2n,
                                                   float* __restrict__ sums,
                                                   int* __restrict__ ticket,
                                                   float* __restrict__ out,
                                                   int N) {
    const int s = blockIdx.x;
    const int w = blockIdx.y;
    const float* z  = w ? z2 : z1;
    const float* gp = w ? g2n : g1n;
    const float* gc = w ? g1n : g2n;
    const int*   o  = off + w * NUM_GRAPHS;
    const int start = o[s];
    const int end   = (s == NUM_GRAPHS - 1) ? N : o[s + 1];

    const int t   = threadIdx.x;
    const int q   = t & 3;
    const int rid = t >> 2;

    float4 gpv[8], gcv[8];
    {
        const float4* GP = reinterpret_cast<const float4*>(gp) + (size_t)s * 32 + q * 8;
        const float4* GC = reinterpret_cast<const float4*>(gc) + (size_t)s * 32 + q * 8;
#pragma unroll
        for (int i = 0; i < 8; ++i) { gpv[i] = GP[i]; gcv[i] = GC[i]; }
    }

    const float4* Z = reinterpret_cast<const float4*>(z);
    float acc = 0.f;
    for (int row = start + rid; row < end; row += 64) {
        float p = 0.f, cr = 0.f, ss = 0.f;
#pragma unroll
        for (int i = 0; i < 8; ++i) {
            float4 zv = Z[(size_t)row * 32 + q * 8 + i];
            p  += zv.x * gpv[i].x + zv.y * gpv[i].y + zv.z * gpv[i].z + zv.w * gpv[i].w;
            cr += zv.x * gcv[i].x + zv.y * gcv[i].y + zv.z * gcv[i].z + zv.w * gcv[i].w;
            ss += zv.x * zv.x + zv.y * zv.y + zv.z * zv.z + zv.w * zv.w;
        }
        p  += __shfl_xor(p, 1, 64);  p  += __shfl_xor(p, 2, 64);
        cr += __shfl_xor(cr, 1, 64); cr += __shfl_xor(cr, 2, 64);
        ss += __shfl_xor(ss, 1, 64); ss += __shfl_xor(ss, 2, 64);
        if (q == 0) {
            const float invz  = 1.0f / fmaxf(sqrtf(ss), 1e-12f);
            const float pos   = p  * invz;
            const float cross = cr * invz;
            const float d = log1pf(__expf(-cross)) - log1pf(__expf(-pos));
            acc += d * d;
        }
    }

    // block reduce (acc nonzero only on q==0 lanes)
#pragma unroll
    for (int m = 1; m <= 32; m <<= 1) acc += __shfl_xor(acc, m, 64);
    __shared__ float warr[4];
    if ((t & 63) == 0) warr[t >> 6] = acc;
    __syncthreads();
    if (t == 0) {
        atomicAdd(&sums[w], warr[0] + warr[1] + warr[2] + warr[3]);
        __threadfence();                        // sums visible before ticket
        const int old = atomicAdd(ticket, 1);   // device-scope
        if (old == DOTS_GRID - 1) {             // I'm last: all sums landed
            __threadfence();
            const float s0 = __hip_atomic_load(&sums[0], __ATOMIC_RELAXED,
                                               __HIP_MEMORY_SCOPE_AGENT);
            const float s1 = __hip_atomic_load(&sums[1], __ATOMIC_RELAXED,
                                               __HIP_MEMORY_SCOPE_AGENT);
            out[0] = sqrtf(s0) + sqrtf(s1);
        }
    }
}

extern "C" void kernel_launch(void* const* d_in, const int* in_sizes, int n_in,
                              void* d_out, int out_size, void* d_ws, size_t ws_size,
                              hipStream_t stream) {
    const float* z1 = (const float*)d_in[0];
    const float* z2 = (const float*)d_in[1];
    const int*   b1 = (const int*)d_in[2];
    const int*   b2 = (const int*)d_in[3];
    const int N = in_sizes[2];

    int*   off    = (int*)d_ws;                        // 1024 ints
    float* g1n    = (float*)(off + 2 * NUM_GRAPHS);    // 512*128 floats
    float* g2n    = g1n + NUM_GRAPHS * D;              // 512*128 floats
    float* sums   = g2n + NUM_GRAPHS * D;              // 2 floats
    int*   ticket = (int*)(sums + 2);                  // 1 int

    bounds_kernel<<<4, 256, 0, stream>>>(b1, b2, off, sums, ticket, N);
    dim3 grid(NUM_GRAPHS, 2);
    seg_norm_kernel<<<grid, 256, 0, stream>>>(z1, z2, off, g1n, g2n, N);
    dots_kernel<<<grid, 256, 0, stream>>>(z1, z2, off, g1n, g2n, sums, ticket,
                                          (float*)d_out, N);
}

// Round 6
// 55.757 us; speedup vs baseline: 1.4441x; 1.4441x over previous
//
#include <hip/hip_runtime.h>
#include <math.h>

#define NUM_GRAPHS 512
#define D 128

__device__ inline int lower_bound_i(const int* __restrict__ b, int n, int v) {
    int lo = 0, hi = n;
    while (lo < hi) {
        int mid = (lo + hi) >> 1;
        if (b[mid] < v) lo = mid + 1; else hi = mid;
    }
    return lo;
}

__device__ inline void add4(float4& a, const float4 v) {
    a.x += v.x; a.y += v.y; a.z += v.z; a.w += v.w;
}

// K0: one binary search per (segment, modality) + zero the sums accumulators
// (replaces the hipMemsetAsync -> fillBufferAligned dispatch).
__global__ void bounds_kernel(const int* __restrict__ b1,
                              const int* __restrict__ b2,
                              int* __restrict__ off,
                              float* __restrict__ sums, int N) {
    const int t = blockIdx.x * blockDim.x + threadIdx.x;
    if (t < NUM_GRAPHS)            off[t] = lower_bound_i(b1, N, t);
    else if (t < 2 * NUM_GRAPHS)   off[t] = lower_bound_i(b2, N, t - NUM_GRAPHS);
    if (t == 0) { sums[0] = 0.f; sums[1] = 0.f; }
}

// K1: segment sum + L2-normalize, store normalized g. grid (512,2), block 256.
// Thread t: row-group r=t>>5 (8 rows/group), float4 col c=t&31.
// 4 independent accumulators -> 4 loads in flight per lane.
__global__ __launch_bounds__(256) void seg_norm_kernel(const float* __restrict__ z1,
                                                       const float* __restrict__ z2,
                                                       const int* __restrict__ off,
                                                       float* __restrict__ g1n,
                                                       float* __restrict__ g2n,
                                                       int N) {
    const int s = blockIdx.x;
    const int w = blockIdx.y;
    const float* z = w ? z2 : z1;
    float*       g = w ? g2n : g1n;
    const int*   o = off + w * NUM_GRAPHS;
    const int start = o[s];
    const int end   = (s == NUM_GRAPHS - 1) ? N : o[s + 1];

    const int t = threadIdx.x;
    const int r = t >> 5;   // 0..7
    const int c = t & 31;   // float4 col
    const float4* Z = reinterpret_cast<const float4*>(z);

    float4 a0 = make_float4(0.f, 0.f, 0.f, 0.f), a1 = a0, a2 = a0, a3 = a0;
    int row = start + r;
    for (; row + 24 < end; row += 32) {
        float4 v0 = Z[(size_t)row * 32 + c];
        float4 v1 = Z[(size_t)(row + 8)  * 32 + c];
        float4 v2 = Z[(size_t)(row + 16) * 32 + c];
        float4 v3 = Z[(size_t)(row + 24) * 32 + c];
        add4(a0, v0); add4(a1, v1); add4(a2, v2); add4(a3, v3);
    }
    for (; row < end; row += 8) add4(a0, Z[(size_t)row * 32 + c]);
    add4(a0, a1); add4(a2, a3); add4(a0, a2);

    __shared__ float4 part[8][32];
    part[r][c] = a0;
    __syncthreads();
    if (t < 32) {
        float4 sum = part[0][t];
#pragma unroll
        for (int gg = 1; gg < 8; ++gg) add4(sum, part[gg][t]);
        float ss = sum.x * sum.x + sum.y * sum.y + sum.z * sum.z + sum.w * sum.w;
#pragma unroll
        for (int m = 1; m <= 16; m <<= 1) ss += __shfl_xor(ss, m, 64);
        const float inv = 1.0f / fmaxf(sqrtf(ss), 1e-12f);
        sum.x *= inv; sum.y *= inv; sum.z *= inv; sum.w *= inv;
        reinterpret_cast<float4*>(g)[(size_t)s * 32 + t] = sum;
    }
}

// K2: per-row dots + JSD. grid (512,2), block 256. Quad-per-row: q=t&3 owns
// 32 floats (8 float4). g vectors in registers. Plain atomicAdd per block —
// NO threadfence / ticket (R5 showed per-block device fences thrash L2/L3:
// dots 15->55us, FETCH doubled). Kernel boundary orders sums for finalize.
__global__ __launch_bounds__(256) void dots_kernel(const float* __restrict__ z1,
                                                   const float* __restrict__ z2,
                                                   const int* __restrict__ off,
                                                   const float* __restrict__ g1n,
                                                   const float* __restrict__ g2n,
                                                   float* __restrict__ sums,
                                                   int N) {
    const int s = blockIdx.x;
    const int w = blockIdx.y;
    const float* z  = w ? z2 : z1;
    const float* gp = w ? g2n : g1n;
    const float* gc = w ? g1n : g2n;
    const int*   o  = off + w * NUM_GRAPHS;
    const int start = o[s];
    const int end   = (s == NUM_GRAPHS - 1) ? N : o[s + 1];

    const int t   = threadIdx.x;
    const int q   = t & 3;
    const int rid = t >> 2;

    float4 gpv[8], gcv[8];
    {
        const float4* GP = reinterpret_cast<const float4*>(gp) + (size_t)s * 32 + q * 8;
        const float4* GC = reinterpret_cast<const float4*>(gc) + (size_t)s * 32 + q * 8;
#pragma unroll
        for (int i = 0; i < 8; ++i) { gpv[i] = GP[i]; gcv[i] = GC[i]; }
    }

    const float4* Z = reinterpret_cast<const float4*>(z);
    float acc = 0.f;
    for (int row = start + rid; row < end; row += 64) {
        float p = 0.f, cr = 0.f, ss = 0.f;
#pragma unroll
        for (int i = 0; i < 8; ++i) {
            float4 zv = Z[(size_t)row * 32 + q * 8 + i];
            p  += zv.x * gpv[i].x + zv.y * gpv[i].y + zv.z * gpv[i].z + zv.w * gpv[i].w;
            cr += zv.x * gcv[i].x + zv.y * gcv[i].y + zv.z * gcv[i].z + zv.w * gcv[i].w;
            ss += zv.x * zv.x + zv.y * zv.y + zv.z * zv.z + zv.w * zv.w;
        }
        p  += __shfl_xor(p, 1, 64);  p  += __shfl_xor(p, 2, 64);
        cr += __shfl_xor(cr, 1, 64); cr += __shfl_xor(cr, 2, 64);
        ss += __shfl_xor(ss, 1, 64); ss += __shfl_xor(ss, 2, 64);
        if (q == 0) {
            const float invz  = 1.0f / fmaxf(sqrtf(ss), 1e-12f);
            const float pos   = p  * invz;
            const float cross = cr * invz;
            const float d = log1pf(__expf(-cross)) - log1pf(__expf(-pos));
            acc += d * d;
        }
    }

    // block reduce (acc nonzero only on q==0 lanes; butterfly sums them all)
#pragma unroll
    for (int m = 1; m <= 32; m <<= 1) acc += __shfl_xor(acc, m, 64);
    __shared__ float warr[4];
    if ((t & 63) == 0) warr[t >> 6] = acc;
    __syncthreads();
    if (t == 0) atomicAdd(&sums[w], warr[0] + warr[1] + warr[2] + warr[3]);
}

__global__ void finalize_kernel(const float* __restrict__ sums,
                                float* __restrict__ out) {
    out[0] = sqrtf(sums[0]) + sqrtf(sums[1]);
}

extern "C" void kernel_launch(void* const* d_in, const int* in_sizes, int n_in,
                              void* d_out, int out_size, void* d_ws, size_t ws_size,
                              hipStream_t stream) {
    const float* z1 = (const float*)d_in[0];
    const float* z2 = (const float*)d_in[1];
    const int*   b1 = (const int*)d_in[2];
    const int*   b2 = (const int*)d_in[3];
    const int N = in_sizes[2];

    int*   off  = (int*)d_ws;                          // 1024 ints
    float* g1n  = (float*)(off + 2 * NUM_GRAPHS);      // 512*128 floats
    float* g2n  = g1n + NUM_GRAPHS * D;                // 512*128 floats
    float* sums = g2n + NUM_GRAPHS * D;                // 2 floats

    bounds_kernel<<<4, 256, 0, stream>>>(b1, b2, off, sums, N);
    dim3 grid(NUM_GRAPHS, 2);
    seg_norm_kernel<<<grid, 256, 0, stream>>>(z1, z2, off, g1n, g2n, N);
    dots_kernel<<<grid, 256, 0, stream>>>(z1, z2, off, g1n, g2n, sums, N);
    finalize_kernel<<<1, 1, 0, stream>>>(sums, (float*)d_out);
}

// Round 7
// 43.023 us; speedup vs baseline: 1.8715x; 1.2960x over previous
//
#include <hip/hip_runtime.h>
#include <math.h>

#define NUM_GRAPHS 512
#define D 128

__device__ inline int lower_bound_i(const int* __restrict__ b, int n, int v) {
    int lo = 0, hi = n;
    while (lo < hi) {
        int mid = (lo + hi) >> 1;
        if (b[mid] < v) lo = mid + 1; else hi = mid;
    }
    return lo;
}

__device__ inline void add4(float4& a, const float4 v) {
    a.x += v.x; a.y += v.y; a.z += v.z; a.w += v.w;
}

// One block per segment s, 512 threads. Lower half (tt=t&255, t<256) handles
// modality 1, upper half modality 2 — both g vectors are block-local, so no
// cross-block dependency, no grid sync, no atomics.
// Phase A: segment sum (float4, 4 accumulators). Phase B: normalize into LDS.
// Phase C: quad-per-row dots vs g (own+other) from LDS->regs; JSD; block
// reduce; plain store to dsq[half*512+s] (no zero-init needed).
__global__ __launch_bounds__(512, 4) void fused_gcl(
    const float* __restrict__ z1, const float* __restrict__ z2,
    const int* __restrict__ b1, const int* __restrict__ b2,
    float* __restrict__ dsq, int N)
{
    const int s    = blockIdx.x;
    const int t    = threadIdx.x;
    const int half = t >> 8;     // 0: z1/b1, 1: z2/b2
    const int tt   = t & 255;

    const float* z = half ? z2 : z1;
    const int*   b = half ? b2 : b1;

    __shared__ int    bnds[2][2];
    __shared__ float4 part[2][8][32];
    __shared__ float  gbuf[2][D];
    __shared__ float  warr[2][4];

    if (tt < 2) bnds[half][tt] = lower_bound_i(b, N, s + tt);
    __syncthreads();
    const int start = bnds[half][0], end = bnds[half][1];

    // ---- Phase A: segment sum ----
    {
        const int r = tt >> 5;   // 0..7
        const int c = tt & 31;   // float4 col
        const float4* Z = reinterpret_cast<const float4*>(z);
        float4 a0 = make_float4(0.f, 0.f, 0.f, 0.f), a1 = a0, a2 = a0, a3 = a0;
        int row = start + r;
        for (; row + 24 < end; row += 32) {
            float4 v0 = Z[(size_t)row * 32 + c];
            float4 v1 = Z[(size_t)(row + 8)  * 32 + c];
            float4 v2 = Z[(size_t)(row + 16) * 32 + c];
            float4 v3 = Z[(size_t)(row + 24) * 32 + c];
            add4(a0, v0); add4(a1, v1); add4(a2, v2); add4(a3, v3);
        }
        for (; row < end; row += 8) add4(a0, Z[(size_t)row * 32 + c]);
        add4(a0, a1); add4(a2, a3); add4(a0, a2);
        part[half][r][c] = a0;
    }
    __syncthreads();

    // ---- Phase B: reduce + normalize (lanes 0..31 of wave 0 of each half) ----
    if (tt < 32) {
        float4 sum = part[half][0][tt];
#pragma unroll
        for (int g = 1; g < 8; ++g) add4(sum, part[half][g][tt]);
        float ss = sum.x * sum.x + sum.y * sum.y + sum.z * sum.z + sum.w * sum.w;
#pragma unroll
        for (int m = 1; m <= 16; m <<= 1) ss += __shfl_xor(ss, m, 64);
        const float inv = 1.0f / fmaxf(sqrtf(ss), 1e-12f);
        sum.x *= inv; sum.y *= inv; sum.z *= inv; sum.w *= inv;
        reinterpret_cast<float4*>(gbuf[half])[tt] = sum;
    }
    __syncthreads();

    // ---- Phase C: dots + JSD (re-read own segment; L2/L3-resident) ----
    const int q   = tt & 3;
    const int rid = tt >> 2;
    float4 gpv[8], gcv[8];
    {
        const float4* GP = reinterpret_cast<const float4*>(gbuf[half])     + q * 8;
        const float4* GC = reinterpret_cast<const float4*>(gbuf[half ^ 1]) + q * 8;
#pragma unroll
        for (int i = 0; i < 8; ++i) { gpv[i] = GP[i]; gcv[i] = GC[i]; }
    }

    const float4* Z = reinterpret_cast<const float4*>(z);
    float acc = 0.f;
    for (int row = start + rid; row < end; row += 64) {
        float p = 0.f, cr = 0.f, ss = 0.f;
#pragma unroll
        for (int i = 0; i < 8; ++i) {
            float4 zv = Z[(size_t)row * 32 + q * 8 + i];
            p  += zv.x * gpv[i].x + zv.y * gpv[i].y + zv.z * gpv[i].z + zv.w * gpv[i].w;
            cr += zv.x * gcv[i].x + zv.y * gcv[i].y + zv.z * gcv[i].z + zv.w * gcv[i].w;
            ss += zv.x * zv.x + zv.y * zv.y + zv.z * zv.z + zv.w * zv.w;
        }
        p  += __shfl_xor(p, 1, 64);  p  += __shfl_xor(p, 2, 64);
        cr += __shfl_xor(cr, 1, 64); cr += __shfl_xor(cr, 2, 64);
        ss += __shfl_xor(ss, 1, 64); ss += __shfl_xor(ss, 2, 64);
        if (q == 0) {
            const float invz  = 1.0f / fmaxf(sqrtf(ss), 1e-12f);
            const float pos   = p  * invz;
            const float cross = cr * invz;
            const float d = log1pf(__expf(-cross)) - log1pf(__expf(-pos));
            acc += d * d;
        }
    }

#pragma unroll
    for (int m = 1; m <= 32; m <<= 1) acc += __shfl_xor(acc, m, 64);
    if ((tt & 63) == 0) warr[half][tt >> 6] = acc;
    __syncthreads();
    if (tt == 0)
        dsq[half * NUM_GRAPHS + s] = warr[half][0] + warr[half][1]
                                   + warr[half][2] + warr[half][3];
}

// Single block, 1024 threads: sum dsq[0..511] -> s0, dsq[512..1023] -> s1.
// Wave boundaries align with the halves (waves 0-7 are w=0, 8-15 are w=1).
__global__ __launch_bounds__(1024) void finalize_kernel(const float* __restrict__ dsq,
                                                        float* __restrict__ out) {
    const int t = threadIdx.x;
    float v = dsq[t];
#pragma unroll
    for (int m = 1; m <= 32; m <<= 1) v += __shfl_xor(v, m, 64);
    __shared__ float w[16];
    if ((t & 63) == 0) w[t >> 6] = v;
    __syncthreads();
    if (t == 0) {
        float s0 = 0.f, s1 = 0.f;
#pragma unroll
        for (int i = 0; i < 8; ++i)  s0 += w[i];
#pragma unroll
        for (int i = 8; i < 16; ++i) s1 += w[i];
        out[0] = sqrtf(s0) + sqrtf(s1);
    }
}

extern "C" void kernel_launch(void* const* d_in, const int* in_sizes, int n_in,
                              void* d_out, int out_size, void* d_ws, size_t ws_size,
                              hipStream_t stream) {
    const float* z1 = (const float*)d_in[0];
    const float* z2 = (const float*)d_in[1];
    const int*   b1 = (const int*)d_in[2];
    const int*   b2 = (const int*)d_in[3];
    const int N = in_sizes[2];

    float* dsq = (float*)d_ws;   // 1024 floats, fully written every call

    fused_gcl<<<NUM_GRAPHS, 512, 0, stream>>>(z1, z2, b1, b2, dsq, N);
    finalize_kernel<<<1, 1024, 0, stream>>>(dsq, (float*)d_out);
}